// Round 1
// baseline (9596.185 us; speedup 1.0000x reference)
//
#include <hip/hip_runtime.h>
#include <stdint.h>

#define ALPHA 0.9f
#define NB   32
#define NT   256
#define NIN  512
#define NH   2048
#define NOUT 512

#define NWG  256
#define NTHR 256

// workspace layout (bytes)
#define WS_CNT 0              // u32 arrival counter (monotonic)
#define WS_GEN 128            // u32 generation flag
#define WS_SHB 256            // hidden spike bytes, double buffer: [p][b][256] = 16384
#define WS_SIN (256 + 16384)  // s_in bits for all steps: [t][b][8 u64] = 524288

typedef unsigned long long u64;
typedef uint32_t u32;
typedef uint8_t  u8;

// ---------------- Kernel 1: precompute input-population spikes for all t ----------------
__global__ void snn_prep(const float* __restrict__ x, u8* __restrict__ ws) {
    int g = blockIdx.x * blockDim.x + threadIdx.x;   // 0..16383 = b*512 + i
    int b = g >> 9;
    int i = g & 511;
    u64* sw = (u64*)(ws + WS_SIN);
    const float* xp = x + (size_t)b * NT * NIN + i;
    float v = 0.f;
    int lane = threadIdx.x & 63;
    for (int t = 0; t < NT; ++t) {
        float vn = ALPHA * v + xp[(size_t)t * NIN];
        bool sp = (vn >= 1.0f);
        v = sp ? 0.f : vn;
        u64 m = __ballot(sp);
        if (lane == 0) sw[(size_t)t * (NB * 8) + b * 8 + (i >> 6)] = m;
    }
}

// ---------------- Kernel 2: persistent recurrent kernel, 1 global barrier per step ----------------
__launch_bounds__(NTHR, 1)
__global__ void snn_main(const float* __restrict__ W1,
                         const float* __restrict__ Wr,
                         const float* __restrict__ W2,
                         float* __restrict__ out,
                         u8* __restrict__ ws)
{
    const int wg  = blockIdx.x;     // 0..255: owns hidden cols [wg*8, wg*8+8), out cols [wg*2, wg*2+2)
    const int tid = threadIdx.x;

    // LDS: 10240 + 36864 + 1024 + 256 + 256 = 48.6 KB
    __shared__ u64   sbits[40][32];   // [k-word][b]: words 0..7 = s_in(t), 8..39 = s_h(t-1)
    __shared__ float pool[9216];      // spike f32 chunk [256][36] / aliased partial-sum buffers
    __shared__ float vh_l[256];       // v_h for (b, owned j) ; o = b*8+j
    __shared__ float vo_l[64];        // v_out (b, owned 2 cols)
    __shared__ float ao_l[64];        // acc_out

    u32* cnt = (u32*)(ws + WS_CNT);
    u32* gen = (u32*)(ws + WS_GEN);
    u8*  shb = ws + WS_SHB;
    u64* sinw = (u64*)(ws + WS_SIN);

    for (int i2 = tid; i2 < 256; i2 += NTHR) vh_l[i2] = 0.f;
    if (tid < 64) { vo_l[tid] = 0.f; ao_l[tid] = 0.f; }

    // hidden GEMM thread map: (ks 0..15, b4 0..7, j4 0..1) -> 4b x 4j tile, k-slice of 16 per 256-chunk
    const int j4  = tid & 1;
    const int b4  = (tid >> 1) & 7;
    const int ks  = tid >> 4;
    // out GEMM thread map: (ks2 0..31, b4o 0..7) -> 4b x 2j tile, k-slice of 8 per chunk
    const int b4o = tid & 7;
    const int ks2 = tid >> 3;
    const int jb  = wg * 8;
    const int jbo = wg * 2;
    const int sb  = tid >> 3, swd = tid & 7;   // s_in staging map

    float accH[16];
    float accO[8];

    for (int t = 0; t <= NT; ++t) {
        // ---- wait until s_h(t-1) published by all WGs ----
        if (t > 0) {
            if (tid == 0) {
                while (__hip_atomic_load(gen, __ATOMIC_RELAXED, __HIP_MEMORY_SCOPE_AGENT) < (u32)t)
                    __builtin_amdgcn_s_sleep(2);
            }
            __syncthreads();
        }
        // ---- stage s_in(t) bits -> LDS words 0..7 ----
        {
            u64 v = 0;
            if (t < NT) v = sinw[(size_t)t * (NB * 8) + sb * 8 + swd];
            sbits[swd][sb] = v;
        }
        // ---- issue s_h(t-1) loads (LLC) into regs; consumed before chunk 2 (latency hidden) ----
        u64 shreg[4];
        #pragma unroll
        for (int r = 0; r < 4; ++r) {
            int g = tid + (r << 8);          // 0..1023
            int b = g >> 5, w = g & 31;
            shreg[r] = 0;
            if (t > 0) {
                u64* src = (u64*)(shb + ((t - 1) & 1) * (NB * 256));
                shreg[r] = __hip_atomic_load(&src[b * 32 + w], __ATOMIC_RELAXED, __HIP_MEMORY_SCOPE_AGENT);
            }
        }
        __syncthreads();

        #pragma unroll
        for (int q = 0; q < 16; ++q) accH[q] = 0.f;
        #pragma unroll
        for (int q = 0; q < 8;  ++q) accO[q] = 0.f;

        const bool doH = (t < NT);
        const bool doO = (t > 0);

        // ---- 10 chunks of 256 k: 0..1 = s_in@W1 ; 2..9 = s_h@Wr (+ s_h@W2 for out) ----
        for (int c = 0; c < 10; ++c) {
            if (c == 2) {   // s_h bits now needed: commit staged regs to LDS
                #pragma unroll
                for (int r = 0; r < 4; ++r) {
                    int g = tid + (r << 8);
                    int b = g >> 5, w = g & 31;
                    sbits[8 + w][b] = shreg[r];
                }
                __syncthreads();
            }
            // expand chunk bits -> f32 spikes pool[kc][b] (stride 36 to spread banks)
            {
                int eb  = tid & 31;
                int kc0 = tid >> 5;
                const u8* sb8 = (const u8*)sbits;
                #pragma unroll 8
                for (int r = 0; r < 32; ++r) {
                    int kc = kc0 + (r << 3);
                    int kk = (c << 8) + kc;
                    u8 byte = sb8[((kk >> 6) * 32 + eb) * 8 + ((kk >> 3) & 7)];
                    pool[kc * 36 + eb] = ((byte >> (kk & 7)) & 1) ? 1.0f : 0.0f;
                }
            }
            __syncthreads();

            if (doH) {
                const float* Wc = (c < 2) ? (W1 + (size_t)(c << 8) * NH)
                                          : (Wr + (size_t)((c - 2) << 8) * NH);
                #pragma unroll
                for (int ii = 0; ii < 4; ++ii) {
                    int kc4 = ks * 16 + ii * 4;
                    #pragma unroll
                    for (int u = 0; u < 4; ++u) {
                        int kc = kc4 + u;
                        const float4 w4 = *reinterpret_cast<const float4*>(Wc + (size_t)kc * NH + jb + j4 * 4);
                        const float4 s4 = *reinterpret_cast<const float4*>(&pool[kc * 36 + b4 * 4]);
                        const float* wf = reinterpret_cast<const float*>(&w4);
                        const float* sf = reinterpret_cast<const float*>(&s4);
                        #pragma unroll
                        for (int bb = 0; bb < 4; ++bb)
                            #pragma unroll
                            for (int jj = 0; jj < 4; ++jj)
                                accH[bb * 4 + jj] += sf[bb] * wf[jj];
                    }
                }
            }
            if (doO && c >= 2) {
                const float* W2c = W2 + (size_t)((c - 2) << 8) * NOUT;
                #pragma unroll
                for (int ii = 0; ii < 2; ++ii) {
                    int kc4 = ks2 * 8 + ii * 4;
                    #pragma unroll
                    for (int u = 0; u < 4; ++u) {
                        int kc = kc4 + u;
                        const float2 w2 = *reinterpret_cast<const float2*>(W2c + (size_t)kc * NOUT + jbo);
                        const float4 s4 = *reinterpret_cast<const float4*>(&pool[kc * 36 + b4o * 4]);
                        const float* sf = reinterpret_cast<const float*>(&s4);
                        #pragma unroll
                        for (int bb = 0; bb < 4; ++bb) {
                            accO[bb * 2 + 0] += sf[bb] * w2.x;
                            accO[bb * 2 + 1] += sf[bb] * w2.y;
                        }
                    }
                }
            }
            __syncthreads();
        }

        // ---- K-split partial reduction (alias pool) ----
        float* redH = pool;          // 4096 slots
        float* redO = pool + 4096;   // 2048 slots
        if (doH) {
            #pragma unroll
            for (int bb = 0; bb < 4; ++bb)
                #pragma unroll
                for (int jj = 0; jj < 4; ++jj)
                    redH[(bb * 4 + jj) * 256 + ks * 16 + b4 * 2 + j4] = accH[bb * 4 + jj];
        }
        if (doO) {
            #pragma unroll
            for (int bb = 0; bb < 4; ++bb)
                #pragma unroll
                for (int jj = 0; jj < 2; ++jj)
                    redO[(bb * 2 + jj) * 256 + ks2 * 8 + b4o] = accO[bb * 2 + jj];
        }
        __syncthreads();

        // ---- hidden LIF + publish spike byte per (b, wg) ----
        if (doH) {
            int b = tid >> 3, j = tid & 7;
            int bb = b & 3, b4r = b >> 2, jj = j & 3, j4r = j >> 2;
            float s = 0.f;
            #pragma unroll
            for (int k2 = 0; k2 < 16; ++k2)
                s += redH[(bb * 4 + jj) * 256 + k2 * 16 + b4r * 2 + j4r];
            float vn = ALPHA * vh_l[tid] + s;
            bool sp = (vn >= 1.0f);
            vh_l[tid] = sp ? 0.f : vn;
            u64 m = __ballot(sp);
            if ((tid & 7) == 0) {
                u8 byte = (u8)((m >> (tid & 63)) & 0xFFull);
                __hip_atomic_store(shb + (t & 1) * (NB * 256) + b * 256 + wg, byte,
                                   __ATOMIC_RELAXED, __HIP_MEMORY_SCOPE_AGENT);
            }
        }
        // ---- out LIF (step t-1) + accumulate ----
        if (doO && tid < 64) {
            int b = tid >> 1, jj = tid & 1;
            int bb = b & 3, b4r = b >> 2;
            float s = 0.f;
            #pragma unroll
            for (int k2 = 0; k2 < 32; ++k2)
                s += redO[(bb * 2 + jj) * 256 + k2 * 8 + b4r];
            float vn = ALPHA * vo_l[tid] + s;
            bool sp = (vn >= 1.0f);
            vo_l[tid] = sp ? 0.f : vn;
            ao_l[tid] += sp ? 1.0f : 0.0f;
        }

        // ---- global barrier arrive (release orders this WG's publishes) ----
        if (t < NT) {
            __syncthreads();   // drains each thread's publish stores (vmcnt) before arrive
            if (tid == 0) {
                u32 old = __hip_atomic_fetch_add(cnt, 1u, __ATOMIC_RELEASE, __HIP_MEMORY_SCOPE_AGENT);
                if (old == (u32)(NWG * (t + 1) - 1))
                    __hip_atomic_store(gen, (u32)(t + 1), __ATOMIC_RELAXED, __HIP_MEMORY_SCOPE_AGENT);
            }
        }
    }

    __syncthreads();
    if (tid < 64) {
        int b = tid >> 1, jj = tid & 1;
        out[b * NOUT + jbo + jj] = ao_l[tid];
    }
}

extern "C" void kernel_launch(void* const* d_in, const int* in_sizes, int n_in,
                              void* d_out, int out_size, void* d_ws, size_t ws_size,
                              hipStream_t stream)
{
    const float* x  = (const float*)d_in[0];
    const float* W1 = (const float*)d_in[1];
    const float* Wr = (const float*)d_in[2];
    const float* W2 = (const float*)d_in[3];
    float* out = (float*)d_out;
    u8* ws = (u8*)d_ws;
    (void)in_sizes; (void)n_in; (void)out_size; (void)ws_size;

    // barrier words must be zero every call (ws is poisoned 0xAA by the harness)
    hipMemsetAsync(ws, 0, 256, stream);

    hipLaunchKernelGGL(snn_prep, dim3(64), dim3(256), 0, stream, x, ws);

    void* args[] = { (void*)&W1, (void*)&Wr, (void*)&W2, (void*)&out, (void*)&ws };
    hipLaunchCooperativeKernel(reinterpret_cast<void*>(snn_main),
                               dim3(NWG), dim3(NTHR), args, 0, stream);
}

// Round 5
// 4777.322 us; speedup vs baseline: 2.0087x; 2.0087x over previous
//
#include <hip/hip_runtime.h>
#include <stdint.h>

#define ALPHA 0.9f
#define NB   32
#define NT   256
#define NIN  512
#define NH   2048
#define NOUT 512

#define NWG  256
#define NTHR 256

// workspace layout (bytes)
#define WS_CNT 0              // u32 arrival counter (monotonic)
#define WS_GEN 128            // u32 generation flag
#define WS_SHB 256            // hidden spike bytes, double buffer: [p][w][b][8] = 16384
#define WS_SIN (256 + 16384)  // s_in bits, word-major: [t][w 0..7][b 0..31] u64 = 524288

typedef unsigned long long u64;
typedef uint32_t u32;
typedef uint8_t  u8;

// dynamic LDS float offsets
#define L_W1   0
#define L_W1S  4096                    // 512 rows x 8
#define L_WR   (L_W1 + L_W1S)          // 4096
#define L_WRS  16384                   // 2048 rows x 8
#define L_W2   (L_WR + L_WRS)          // 20480
#define L_W2S  4096                    // 2048 rows x 2
#define L_SB   (L_W2 + L_W2S)          // 24576 floats (byte off 98304, u64-aligned)
#define L_SBS  2560                    // 1280 u64
#define L_RH   (L_SB + L_SBS)          // 27136 ; size 4384
#define L_RHS  4384
#define L_RO   (L_RH + L_RHS)          // 31520 ; size 2112
#define L_ROS  2112
#define L_VH   (L_RO + L_ROS)          // 33632
#define L_VO   (L_VH + 256)            // 33888
#define L_AO   (L_VO + 64)             // 33952
#define L_TOT  (L_AO + 64)             // 34016 floats = 136064 B

// BIJECTIVE XOR row swizzles (round-3 additive versions collided: WSW(61)==WSW(64) etc).
// XOR of low row bits keyed by higher bits is a permutation; spreads the k-split
// groups across all 32 banks for the wave read patterns below.
#define WSW(k)  ((((k) ^ (((k) >> 4) & 3)) ) * 8)
#define W2SW(k) ((((k) ^ (((k) >> 3) & 7)) ) * 2)
// reduction layouts (<=2-way banks on both read and write)
#define RH_IDX(o,p) ((o)*17 + (((o)>>5)<<2) + (p))
#define RO_IDX(o,p) ((o)*33 + (p))

// ---------------- Kernel 1: precompute input-population spikes for all t ----------------
__global__ void snn_prep(const float* __restrict__ x, u8* __restrict__ ws) {
    int g = blockIdx.x * blockDim.x + threadIdx.x;   // 0..16383 = b*512 + i
    int b = g >> 9;
    int i = g & 511;
    u64* sw = (u64*)(ws + WS_SIN);
    const float* xp = x + (size_t)b * NT * NIN + i;
    float v = 0.f;
    int lane = threadIdx.x & 63;
    for (int t = 0; t < NT; ++t) {
        float vn = ALPHA * v + xp[(size_t)t * NIN];
        bool sp = (vn >= 1.0f);
        v = sp ? 0.f : vn;
        u64 m = __ballot(sp);
        if (lane == 0) sw[(size_t)t * 256 + (i >> 6) * 32 + b] = m;  // word-major [t][w][b]
    }
}

// ---------------- Kernel 2: persistent recurrent kernel, 1 global barrier per step ----------------
__launch_bounds__(NTHR, 1)
__global__ void snn_main(const float* __restrict__ W1,
                         const float* __restrict__ Wr,
                         const float* __restrict__ W2,
                         float* __restrict__ out,
                         u8* __restrict__ ws)
{
    const int wg  = blockIdx.x;     // owns hidden cols [wg*8, wg*8+8), out cols [wg*2, wg*2+2)
    const int tid = threadIdx.x;

    extern __shared__ float smem[];
    float* w1l  = smem + L_W1;
    float* wrl  = smem + L_WR;
    float* w2l  = smem + L_W2;
    u64*   sbits = (u64*)(smem + L_SB);   // [word 0..39][b 0..31]
    float* redH = smem + L_RH;
    float* redO = smem + L_RO;
    float* vh_l = smem + L_VH;
    float* vo_l = smem + L_VO;
    float* ao_l = smem + L_AO;

    u32* cnt = (u32*)(ws + WS_CNT);
    u32* gen = (u32*)(ws + WS_GEN);
    u8*  shb = ws + WS_SHB;
    const u64* sinw = (const u64*)(ws + WS_SIN);

    const int jb  = wg * 8;
    const int jbo = wg * 2;

    // ---- stage weight slices into LDS (one-time) ----
    for (int g = tid; g < NIN * 2; g += NTHR) {     // W1: 512 rows x 8 cols, float4
        int k = g >> 1, jh = (g & 1) * 4;
        *(float4*)&w1l[WSW(k) + jh] = *(const float4*)&W1[(size_t)k * NH + jb + jh];
    }
    for (int g = tid; g < NH * 2; g += NTHR) {      // Wr: 2048 rows x 8 cols
        int k = g >> 1, jh = (g & 1) * 4;
        *(float4*)&wrl[WSW(k) + jh] = *(const float4*)&Wr[(size_t)k * NH + jb + jh];
    }
    for (int g = tid; g < NH; g += NTHR) {          // W2: 2048 rows x 2 cols
        *(float2*)&w2l[W2SW(g)] = *(const float2*)&W2[(size_t)g * NOUT + jbo];
    }
    for (int i2 = tid; i2 < 256; i2 += NTHR) vh_l[i2] = 0.f;
    if (tid < 64) { vo_l[tid] = 0.f; ao_l[tid] = 0.f; }

    // hidden GEMM map: (ks 0..15 | b4 0..7 | j4 0..1) -> 4b x 4j tile, k-split 16
    const int j4 = tid & 1;
    const int b4 = (tid >> 1) & 7;
    const int ks = tid >> 4;
    // out GEMM map: (ks2 0..31 | b4o 0..7) -> 4b x 2j tile, k-split 32
    const int b4o = tid & 7;
    const int ks2 = tid >> 3;

    float accH[16];
    float accO[8];

    __syncthreads();   // weights + state visible

    for (int t = 0; t <= NT; ++t) {
        // ---- wait until s_h(t-1) published by all WGs ----
        if (t > 0) {
            if (tid == 0) {
                while (__hip_atomic_load(gen, __ATOMIC_RELAXED, __HIP_MEMORY_SCOPE_AGENT) < (u32)t)
                    __builtin_amdgcn_s_sleep(2);
            }
            __syncthreads();
        }
        // ---- stage s_in(t) words 0..7 (coalesced, word-major) ----
        {
            u64 v = 0;
            if (t < NT) v = sinw[(size_t)t * 256 + tid];
            sbits[tid] = v;
        }
        // ---- issue s_h(t-1) LLC loads into regs; committed at chunk 2 (latency hidden) ----
        u64 shreg[4];
        #pragma unroll
        for (int r = 0; r < 4; ++r) {
            shreg[r] = 0;
            if (t > 0) {
                const u64* src = (const u64*)(shb + ((t - 1) & 1) * 8192);
                shreg[r] = __hip_atomic_load(&src[tid + (r << 8)], __ATOMIC_RELAXED, __HIP_MEMORY_SCOPE_AGENT);
            }
        }
        __syncthreads();

        #pragma unroll
        for (int q = 0; q < 16; ++q) accH[q] = 0.f;
        #pragma unroll
        for (int q = 0; q < 8;  ++q) accO[q] = 0.f;

        const bool doH = (t < NT);
        const bool doO = (t > 0);

        // ---- 10 chunks of 256 k: 0..1 = s_in@W1 ; 2..9 = s_h@Wr (+ s_h@W2 for out) ----
        for (int c = 0; c < 10; ++c) {
            if (c == 2) {   // s_h bits now needed: commit staged regs (contiguous, conflict-free)
                #pragma unroll
                for (int r = 0; r < 4; ++r)
                    sbits[256 + tid + (r << 8)] = shreg[r];
                __syncthreads();
            }
            const int wbase = (c < 2) ? (c * 4) : (8 + (c - 2) * 4);

            if (doH) {
                const float* wl = (c < 2) ? w1l : wrl;
                const int rbase = (c < 2) ? (c << 8) : ((c - 2) << 8);
                // this thread's spike bits: 16 bits per batch, from one u32 half-word each
                u32 sv[4];
                {
                    const u32* sb32 = (const u32*)sbits;
                    const int word = (wbase + (ks >> 2)) * 32;
                    const int hi   = (ks >> 1) & 1;
                    const int sh0  = (ks & 1) * 16;
                    #pragma unroll
                    for (int bb = 0; bb < 4; ++bb)
                        sv[bb] = sb32[(word + b4 * 4 + bb) * 2 + hi] >> sh0;
                }
                #pragma unroll
                for (int ii = 0; ii < 4; ++ii) {
                    #pragma unroll
                    for (int u = 0; u < 4; ++u) {
                        const int q = ii * 4 + u;
                        const int row = rbase + ks * 16 + q;
                        const float4 w4 = *(const float4*)&wl[WSW(row) + j4 * 4];
                        float sf[4];
                        #pragma unroll
                        for (int bb = 0; bb < 4; ++bb)
                            sf[bb] = (float)((sv[bb] >> q) & 1u);
                        #pragma unroll
                        for (int bb = 0; bb < 4; ++bb) {
                            accH[bb * 4 + 0] += sf[bb] * w4.x;
                            accH[bb * 4 + 1] += sf[bb] * w4.y;
                            accH[bb * 4 + 2] += sf[bb] * w4.z;
                            accH[bb * 4 + 3] += sf[bb] * w4.w;
                        }
                    }
                }
            }
            if (doO && c >= 2) {
                const int rbase2 = (c - 2) << 8;
                u32 sv[4];
                {
                    const u32* sb32 = (const u32*)sbits;
                    const int word = (wbase + (ks2 >> 3)) * 32;
                    const int hi   = (ks2 >> 2) & 1;
                    const int sh0  = (ks2 & 3) * 8;
                    #pragma unroll
                    for (int bb = 0; bb < 4; ++bb)
                        sv[bb] = sb32[(word + b4o * 4 + bb) * 2 + hi] >> sh0;
                }
                #pragma unroll
                for (int ii = 0; ii < 2; ++ii) {
                    #pragma unroll
                    for (int u = 0; u < 4; ++u) {
                        const int q = ii * 4 + u;
                        const int row = rbase2 + ks2 * 8 + q;
                        const float2 w2v = *(const float2*)&w2l[W2SW(row)];
                        #pragma unroll
                        for (int bb = 0; bb < 4; ++bb) {
                            float s = (float)((sv[bb] >> q) & 1u);
                            accO[bb * 2 + 0] += s * w2v.x;
                            accO[bb * 2 + 1] += s * w2v.y;
                        }
                    }
                }
            }
        }

        // ---- K-split partial reduction ----
        if (doH) {
            #pragma unroll
            for (int bb = 0; bb < 4; ++bb)
                #pragma unroll
                for (int jj = 0; jj < 4; ++jj) {
                    const int o = (b4 * 4 + bb) * 8 + j4 * 4 + jj;
                    redH[RH_IDX(o, ks)] = accH[bb * 4 + jj];
                }
        }
        if (doO) {
            #pragma unroll
            for (int bb = 0; bb < 4; ++bb)
                #pragma unroll
                for (int jj = 0; jj < 2; ++jj) {
                    const int o = (b4o * 4 + bb) * 2 + jj;
                    redO[RO_IDX(o, ks2)] = accO[bb * 2 + jj];
                }
        }
        __syncthreads();

        // ---- hidden LIF + publish spike byte per (b, wg) ----
        if (doH) {
            float s = 0.f;
            #pragma unroll
            for (int k2 = 0; k2 < 16; ++k2)
                s += redH[RH_IDX(tid, k2)];
            float vn = ALPHA * vh_l[tid] + s;
            bool sp = (vn >= 1.0f);
            vh_l[tid] = sp ? 0.f : vn;
            u64 m = __ballot(sp);
            if ((tid & 7) == 0) {
                int b = tid >> 3;
                u8 byte = (u8)((m >> (tid & 63)) & 0xFFull);
                __hip_atomic_store(shb + (t & 1) * 8192 + ((wg >> 3) * 32 + b) * 8 + (wg & 7),
                                   byte, __ATOMIC_RELAXED, __HIP_MEMORY_SCOPE_AGENT);
            }
        }
        // ---- out LIF (step t-1) + accumulate ----
        if (doO && tid < 64) {
            float s = 0.f;
            #pragma unroll
            for (int k2 = 0; k2 < 32; ++k2)
                s += redO[RO_IDX(tid, k2)];
            float vn = ALPHA * vo_l[tid] + s;
            bool sp = (vn >= 1.0f);
            vo_l[tid] = sp ? 0.f : vn;
            ao_l[tid] += sp ? 1.0f : 0.0f;
        }

        // ---- global barrier arrive (release orders this WG's publishes) ----
        if (t < NT) {
            __syncthreads();   // compiler drains vmcnt before s_barrier
            if (tid == 0) {
                u32 old = __hip_atomic_fetch_add(cnt, 1u, __ATOMIC_RELEASE, __HIP_MEMORY_SCOPE_AGENT);
                if (old == (u32)(NWG * (t + 1) - 1))
                    __hip_atomic_store(gen, (u32)(t + 1), __ATOMIC_RELAXED, __HIP_MEMORY_SCOPE_AGENT);
            }
        }
    }

    __syncthreads();
    if (tid < 64) {
        int b = tid >> 1, jj = tid & 1;
        out[b * NOUT + jbo + jj] = ao_l[tid];
    }
}

extern "C" void kernel_launch(void* const* d_in, const int* in_sizes, int n_in,
                              void* d_out, int out_size, void* d_ws, size_t ws_size,
                              hipStream_t stream)
{
    const float* x  = (const float*)d_in[0];
    const float* W1 = (const float*)d_in[1];
    const float* Wr = (const float*)d_in[2];
    const float* W2 = (const float*)d_in[3];
    float* out = (float*)d_out;
    u8* ws = (u8*)d_ws;
    (void)in_sizes; (void)n_in; (void)out_size; (void)ws_size;

    // allow >64KB dynamic LDS (idempotent, capture-safe host-side attribute)
    hipFuncSetAttribute(reinterpret_cast<const void*>(snn_main),
                        hipFuncAttributeMaxDynamicSharedMemorySize, L_TOT * 4);

    // barrier words must be zero every call (ws is poisoned 0xAA by the harness)
    hipMemsetAsync(ws, 0, 256, stream);

    hipLaunchKernelGGL(snn_prep, dim3(64), dim3(256), 0, stream, x, ws);

    void* args[] = { (void*)&W1, (void*)&Wr, (void*)&W2, (void*)&out, (void*)&ws };
    hipLaunchCooperativeKernel(reinterpret_cast<void*>(snn_main),
                               dim3(NWG), dim3(NTHR), args, L_TOT * 4, stream);
}

// Round 7
// 3811.885 us; speedup vs baseline: 2.5174x; 1.2533x over previous
//
#include <hip/hip_runtime.h>
#include <stdint.h>

#define ALPHA 0.9f
#define NB   32
#define NT   256
#define NIN  512
#define NH   2048
#define NOUT 512

#define NWG  256
#define NTHR 256

// workspace layout (bytes)
#define WS_FLAG 0               // u32 flags[256]: WG w sets flags[w]=t+1 after publishing s_h(t)
#define WS_SHB  1024            // hidden spike bytes, double buffer: [p][w][b][8] = 16384
#define WS_SIN  (1024 + 16384)  // s_in bits, word-major: [t][w 0..7][b 0..31] u64 = 524288

typedef unsigned long long u64;
typedef uint32_t u32;
typedef uint8_t  u8;

// dynamic LDS float offsets
#define L_W1   0
#define L_W1S  4096                    // 512 rows x 8
#define L_WR   (L_W1 + L_W1S)          // 4096
#define L_WRS  16384                   // 2048 rows x 8
#define L_W2   (L_WR + L_WRS)          // 20480
#define L_W2S  4096                    // 2048 rows x 2
#define L_SB   (L_W2 + L_W2S)          // 24576 floats (byte off 98304, u64-aligned)
#define L_SBS  2560                    // 1280 u64
#define L_RH   (L_SB + L_SBS)          // 27136 ; size 4384
#define L_RHS  4384
#define L_RO   (L_RH + L_RHS)          // 31520 ; size 2112
#define L_ROS  2112
#define L_VH   (L_RO + L_ROS)          // 33632
#define L_VO   (L_VH + 256)            // 33888
#define L_AO   (L_VO + 64)             // 33952
#define L_PW   (L_AO + 64)             // 34016 : 4-int poll scratch
#define L_TOT  (L_PW + 4)              // 34020 floats = 136080 B

// BIJECTIVE XOR row swizzles (additive versions collided; XOR is a permutation).
// Spread the k-split groups across all 32 banks for the wave read patterns below.
#define WSW(k)  ((((k) ^ (((k) >> 4) & 3)) ) * 8)
#define W2SW(k) ((((k) ^ (((k) >> 3) & 7)) ) * 2)
// reduction layouts (<=2-way banks on both read and write)
#define RH_IDX(o,p) ((o)*17 + (((o)>>5)<<2) + (p))
#define RO_IDX(o,p) ((o)*33 + (p))

// ---------------- Kernel 1: precompute input-population spikes for all t ----------------
__global__ void snn_prep(const float* __restrict__ x, u8* __restrict__ ws) {
    int g = blockIdx.x * blockDim.x + threadIdx.x;   // 0..16383 = b*512 + i
    int b = g >> 9;
    int i = g & 511;
    u64* sw = (u64*)(ws + WS_SIN);
    const float* xp = x + (size_t)b * NT * NIN + i;
    float v = 0.f;
    int lane = threadIdx.x & 63;
    for (int t = 0; t < NT; ++t) {
        float vn = ALPHA * v + xp[(size_t)t * NIN];
        bool sp = (vn >= 1.0f);
        v = sp ? 0.f : vn;
        u64 m = __ballot(sp);
        if (lane == 0) sw[(size_t)t * 256 + (i >> 6) * 32 + b] = m;  // word-major [t][w][b]
    }
}

// ---------------- Kernel 2: persistent recurrent kernel, flag-array barrier per step ----------------
__launch_bounds__(NTHR, 1)
__global__ void snn_main(const float* __restrict__ W1,
                         const float* __restrict__ Wr,
                         const float* __restrict__ W2,
                         float* __restrict__ out,
                         u8* __restrict__ ws)
{
    const int wg  = blockIdx.x;     // owns hidden cols [wg*8, wg*8+8), out cols [wg*2, wg*2+2)
    const int tid = threadIdx.x;

    extern __shared__ float smem[];
    float* w1l  = smem + L_W1;
    float* wrl  = smem + L_WR;
    float* w2l  = smem + L_W2;
    u64*   sbits = (u64*)(smem + L_SB);   // [word 0..39][b 0..31]
    float* redH = smem + L_RH;
    float* redO = smem + L_RO;
    float* vh_l = smem + L_VH;
    float* vo_l = smem + L_VO;
    float* ao_l = smem + L_AO;
    int*   pollw = (int*)(smem + L_PW);

    u32* flags = (u32*)(ws + WS_FLAG);
    u8*  shb = ws + WS_SHB;
    const u64* sinw = (const u64*)(ws + WS_SIN);

    const int jb  = wg * 8;
    const int jbo = wg * 2;

    // ---- stage weight slices into LDS (one-time) ----
    for (int g = tid; g < NIN * 2; g += NTHR) {     // W1: 512 rows x 8 cols, float4
        int k = g >> 1, jh = (g & 1) * 4;
        *(float4*)&w1l[WSW(k) + jh] = *(const float4*)&W1[(size_t)k * NH + jb + jh];
    }
    for (int g = tid; g < NH * 2; g += NTHR) {      // Wr: 2048 rows x 8 cols
        int k = g >> 1, jh = (g & 1) * 4;
        *(float4*)&wrl[WSW(k) + jh] = *(const float4*)&Wr[(size_t)k * NH + jb + jh];
    }
    for (int g = tid; g < NH; g += NTHR) {          // W2: 2048 rows x 2 cols
        *(float2*)&w2l[W2SW(g)] = *(const float2*)&W2[(size_t)g * NOUT + jbo];
    }
    for (int i2 = tid; i2 < 256; i2 += NTHR) vh_l[i2] = 0.f;
    if (tid < 64) { vo_l[tid] = 0.f; ao_l[tid] = 0.f; }

    // hidden GEMM map: (ks 0..15 | b4 0..7 | j4 0..1) -> 4b x 4j tile, k-split 16
    const int j4 = tid & 1;
    const int b4 = (tid >> 1) & 7;
    const int ks = tid >> 4;
    // out GEMM map: (ks2 0..31 | b4o 0..7) -> 4b x 2j tile, k-split 32
    const int b4o = tid & 7;
    const int ks2 = tid >> 3;

    float accH[16];
    float accO[8];

    __syncthreads();   // weights + state visible

    for (int t = 0; t <= NT; ++t) {
        // ---- stage s_in(t) words 0..7 (coalesced, word-major) ----
        {
            u64 v = 0;
            if (t < NT) v = sinw[(size_t)t * 256 + tid];
            sbits[tid] = v;
        }
        __syncthreads();   // s_in bits visible

        #pragma unroll
        for (int q = 0; q < 16; ++q) accH[q] = 0.f;
        #pragma unroll
        for (int q = 0; q < 8;  ++q) accO[q] = 0.f;

        const bool doH = (t < NT);
        const bool doO = (t > 0);

        // ---- chunks 0..1 (s_in @ W1): independent of s_h(t-1) — runs while other
        //      WGs' publishes propagate, so the flag poll below exits ~immediately ----
        for (int c = 0; c < 2; ++c) {
            if (doH) {
                const int wbase = c * 4;
                const int rbase = c << 8;
                u32 sv[4];
                {
                    const u32* sb32 = (const u32*)sbits;
                    const int word = (wbase + (ks >> 2)) * 32;
                    const int hi   = (ks >> 1) & 1;
                    const int sh0  = (ks & 1) * 16;
                    #pragma unroll
                    for (int bb = 0; bb < 4; ++bb)
                        sv[bb] = sb32[(word + b4 * 4 + bb) * 2 + hi] >> sh0;
                }
                #pragma unroll
                for (int ii = 0; ii < 4; ++ii) {
                    #pragma unroll
                    for (int u = 0; u < 4; ++u) {
                        const int q = ii * 4 + u;
                        const int row = rbase + ks * 16 + q;
                        const float4 w4 = *(const float4*)&w1l[WSW(row) + j4 * 4];
                        float sf[4];
                        #pragma unroll
                        for (int bb = 0; bb < 4; ++bb)
                            sf[bb] = (float)((sv[bb] >> q) & 1u);
                        #pragma unroll
                        for (int bb = 0; bb < 4; ++bb) {
                            accH[bb * 4 + 0] += sf[bb] * w4.x;
                            accH[bb * 4 + 1] += sf[bb] * w4.y;
                            accH[bb * 4 + 2] += sf[bb] * w4.z;
                            accH[bb * 4 + 3] += sf[bb] * w4.w;
                        }
                    }
                }
            }
        }

        // ---- wait for all WGs' s_h(t-1): parallel flag poll (no atomic contention) ----
        u64 shreg[4];
        if (t > 0) {
            const u32 tgt = (u32)t;
            int all_ok;
            do {
                u32 f = __hip_atomic_load(&flags[tid], __ATOMIC_RELAXED, __HIP_MEMORY_SCOPE_AGENT);
                u64 w = __ballot(f >= tgt);
                if ((tid & 63) == 0) pollw[tid >> 6] = (w == ~0ull) ? 1 : 0;
                __syncthreads();
                all_ok = pollw[0] & pollw[1] & pollw[2] & pollw[3];
                __syncthreads();
            } while (!all_ok);
            // fetch s_h(t-1) bytes (publishes are agent-scope; loads bypass L1)
            const u64* src = (const u64*)(shb + ((t - 1) & 1) * 8192);
            #pragma unroll
            for (int r = 0; r < 4; ++r)
                shreg[r] = __hip_atomic_load(&src[tid + (r << 8)], __ATOMIC_RELAXED, __HIP_MEMORY_SCOPE_AGENT);
        } else {
            #pragma unroll
            for (int r = 0; r < 4; ++r) shreg[r] = 0;
        }
        // commit s_h bits to LDS words 8..39 (contiguous, conflict-free)
        #pragma unroll
        for (int r = 0; r < 4; ++r)
            sbits[256 + tid + (r << 8)] = shreg[r];
        __syncthreads();

        // ---- chunks 2..9: s_h @ Wr (+ s_h @ W2 for the step-(t-1) out GEMM) ----
        for (int c = 2; c < 10; ++c) {
            const int wbase = 8 + (c - 2) * 4;

            if (doH) {
                const int rbase = (c - 2) << 8;
                u32 sv[4];
                {
                    const u32* sb32 = (const u32*)sbits;
                    const int word = (wbase + (ks >> 2)) * 32;
                    const int hi   = (ks >> 1) & 1;
                    const int sh0  = (ks & 1) * 16;
                    #pragma unroll
                    for (int bb = 0; bb < 4; ++bb)
                        sv[bb] = sb32[(word + b4 * 4 + bb) * 2 + hi] >> sh0;
                }
                #pragma unroll
                for (int ii = 0; ii < 4; ++ii) {
                    #pragma unroll
                    for (int u = 0; u < 4; ++u) {
                        const int q = ii * 4 + u;
                        const int row = rbase + ks * 16 + q;
                        const float4 w4 = *(const float4*)&wrl[WSW(row) + j4 * 4];
                        float sf[4];
                        #pragma unroll
                        for (int bb = 0; bb < 4; ++bb)
                            sf[bb] = (float)((sv[bb] >> q) & 1u);
                        #pragma unroll
                        for (int bb = 0; bb < 4; ++bb) {
                            accH[bb * 4 + 0] += sf[bb] * w4.x;
                            accH[bb * 4 + 1] += sf[bb] * w4.y;
                            accH[bb * 4 + 2] += sf[bb] * w4.z;
                            accH[bb * 4 + 3] += sf[bb] * w4.w;
                        }
                    }
                }
            }
            if (doO) {
                const int rbase2 = (c - 2) << 8;
                u32 sv[4];
                {
                    const u32* sb32 = (const u32*)sbits;
                    const int word = (wbase + (ks2 >> 3)) * 32;
                    const int hi   = (ks2 >> 2) & 1;
                    const int sh0  = (ks2 & 3) * 8;
                    #pragma unroll
                    for (int bb = 0; bb < 4; ++bb)
                        sv[bb] = sb32[(word + b4o * 4 + bb) * 2 + hi] >> sh0;
                }
                #pragma unroll
                for (int ii = 0; ii < 2; ++ii) {
                    #pragma unroll
                    for (int u = 0; u < 4; ++u) {
                        const int q = ii * 4 + u;
                        const int row = rbase2 + ks2 * 8 + q;
                        const float2 w2v = *(const float2*)&w2l[W2SW(row)];
                        #pragma unroll
                        for (int bb = 0; bb < 4; ++bb) {
                            float s = (float)((sv[bb] >> q) & 1u);
                            accO[bb * 2 + 0] += s * w2v.x;
                            accO[bb * 2 + 1] += s * w2v.y;
                        }
                    }
                }
            }
        }

        // ---- K-split partial reduction ----
        if (doH) {
            #pragma unroll
            for (int bb = 0; bb < 4; ++bb)
                #pragma unroll
                for (int jj = 0; jj < 4; ++jj) {
                    const int o = (b4 * 4 + bb) * 8 + j4 * 4 + jj;
                    redH[RH_IDX(o, ks)] = accH[bb * 4 + jj];
                }
        }
        if (doO) {
            #pragma unroll
            for (int bb = 0; bb < 4; ++bb)
                #pragma unroll
                for (int jj = 0; jj < 2; ++jj) {
                    const int o = (b4o * 4 + bb) * 2 + jj;
                    redO[RO_IDX(o, ks2)] = accO[bb * 2 + jj];
                }
        }
        __syncthreads();

        // ---- hidden LIF + publish spike byte per (b, wg) ----
        if (doH) {
            float s = 0.f;
            #pragma unroll
            for (int k2 = 0; k2 < 16; ++k2)
                s += redH[RH_IDX(tid, k2)];
            float vn = ALPHA * vh_l[tid] + s;
            bool sp = (vn >= 1.0f);
            vh_l[tid] = sp ? 0.f : vn;
            u64 m = __ballot(sp);
            if ((tid & 7) == 0) {
                int b = tid >> 3;
                u8 byte = (u8)((m >> (tid & 63)) & 0xFFull);
                __hip_atomic_store(shb + (t & 1) * 8192 + ((wg >> 3) * 32 + b) * 8 + (wg & 7),
                                   byte, __ATOMIC_RELAXED, __HIP_MEMORY_SCOPE_AGENT);
            }
        }
        // ---- out LIF (step t-1) + accumulate ----
        if (doO && tid < 64) {
            float s = 0.f;
            #pragma unroll
            for (int k2 = 0; k2 < 32; ++k2)
                s += redO[RO_IDX(tid, k2)];
            float vn = ALPHA * vo_l[tid] + s;
            bool sp = (vn >= 1.0f);
            vo_l[tid] = sp ? 0.f : vn;
            ao_l[tid] += sp ? 1.0f : 0.0f;
        }

        // ---- arrival: release-store own flag (after syncthreads drains publish stores) ----
        if (t < NT) {
            __syncthreads();   // compiler emits s_waitcnt vmcnt(0) before s_barrier
            if (tid == 0)
                __hip_atomic_store(&flags[wg], (u32)(t + 1), __ATOMIC_RELEASE, __HIP_MEMORY_SCOPE_AGENT);
        }
    }

    __syncthreads();
    if (tid < 64) {
        int b = tid >> 1, jj = tid & 1;
        out[b * NOUT + jbo + jj] = ao_l[tid];
    }
}

extern "C" void kernel_launch(void* const* d_in, const int* in_sizes, int n_in,
                              void* d_out, int out_size, void* d_ws, size_t ws_size,
                              hipStream_t stream)
{
    const float* x  = (const float*)d_in[0];
    const float* W1 = (const float*)d_in[1];
    const float* Wr = (const float*)d_in[2];
    const float* W2 = (const float*)d_in[3];
    float* out = (float*)d_out;
    u8* ws = (u8*)d_ws;
    (void)in_sizes; (void)n_in; (void)out_size; (void)ws_size;

    // allow >64KB dynamic LDS (idempotent, capture-safe host-side attribute)
    hipFuncSetAttribute(reinterpret_cast<const void*>(snn_main),
                        hipFuncAttributeMaxDynamicSharedMemorySize, L_TOT * 4);

    // flag array must be zero every call (ws is poisoned 0xAA by the harness)
    hipMemsetAsync(ws, 0, 1024, stream);

    hipLaunchKernelGGL(snn_prep, dim3(64), dim3(256), 0, stream, x, ws);

    void* args[] = { (void*)&W1, (void*)&Wr, (void*)&W2, (void*)&out, (void*)&ws };
    hipLaunchCooperativeKernel(reinterpret_cast<void*>(snn_main),
                               dim3(NWG), dim3(NTHR), args, L_TOT * 4, stream);
}